// Round 3
// baseline (2610.125 us; speedup 1.0000x reference)
//
#include <hip/hip_runtime.h>
#include <stdint.h>
#include <math.h>

#define HWS 16384
#define NPIX (16 * HWS)

// float offsets into d_ws for the folded fp32 parameter table
enum {
  OFF_W1  = 0,      // 24x48  rb conv1 (bn-folded)
  OFF_B1  = 1152,   // 24
  OFF_W2  = 1176,   // 48x24  rb conv2 (post-residual bn folded)
  OFF_B2  = 2328,   // 48
  OFF_XS  = 2376,   // 48     bn scale applied to xs in residual add
  OFF_WQ  = 2424,   // 48x48
  OFF_BQ  = 4728,   // 48
  OFF_WV  = 4776,   // 48x48
  OFF_BV  = 7080,   // 48
  OFF_WK1 = 7128,   // 24x48
  OFF_BK1 = 8280,   // 24
  OFF_WK2 = 8304,   // 24x48
  OFF_BK2 = 9456,   // 24
  OFF_WCF = 9480,   // 48x96
  OFF_BCF = 14088,  // 48
  OFF_WE1 = 14136,  // 24x48  emb conv1 (no bn)
  OFF_BE1 = 15288,  // 24
  OFF_WE2 = 15312,  // 48x24
  OFF_BE2 = 16464,  // 48
  WS_TOTAL = 16512
};

struct PtrPack { const float* p[48]; };

// ---------------- fold kernel: f32 params -> f32 folded table ----------------
// bn fold: s = g/sqrt(v+eps), t = beta - m*s;  bn(conv(x,W,b)) = (s.W)x + (s.b + t)
#define SCALE_T(bnb, o, s, t)                                       \
  {                                                                 \
    float g_ = P.p[(bnb)][(o)], be_ = P.p[(bnb) + 1][(o)];          \
    float m_ = P.p[(bnb) + 2][(o)], v_ = P.p[(bnb) + 3][(o)];       \
    s = g_ / sqrtf(v_ + 1e-5f);                                     \
    t = be_ - m_ * s;                                               \
  }

__global__ void fold_kernel(PtrPack P, float* __restrict__ W) {
  int i = blockIdx.x * blockDim.x + threadIdx.x;
  float s, t;
  if (i < OFF_B1)        { int j = i;            int o = j / 48; SCALE_T(4,  o, s, t); W[i] = s * P.p[2][j]; }
  else if (i < OFF_W2)   { int o = i - OFF_B1;                   SCALE_T(4,  o, s, t); W[i] = s * P.p[3][o] + t; }
  else if (i < OFF_B2)   { int j = i - OFF_W2;   int o = j / 24; SCALE_T(10, o, s, t); W[i] = s * P.p[8][j]; }
  else if (i < OFF_XS)   { int o = i - OFF_B2;                   SCALE_T(10, o, s, t); W[i] = s * P.p[9][o] + t; }
  else if (i < OFF_WQ)   { int o = i - OFF_XS;                   SCALE_T(10, o, s, t); W[i] = s; }
  else if (i < OFF_BQ)   { int j = i - OFF_WQ;   int o = j / 48; SCALE_T(16, o, s, t); W[i] = s * P.p[14][j]; }
  else if (i < OFF_WV)   { int o = i - OFF_BQ;                   SCALE_T(16, o, s, t); W[i] = s * P.p[15][o] + t; }
  else if (i < OFF_BV)   { int j = i - OFF_WV;   int o = j / 48; SCALE_T(22, o, s, t); W[i] = s * P.p[20][j]; }
  else if (i < OFF_WK1)  { int o = i - OFF_BV;                   SCALE_T(22, o, s, t); W[i] = s * P.p[21][o] + t; }
  else if (i < OFF_BK1)  { int j = i - OFF_WK1;  int o = j / 48; SCALE_T(28, o, s, t); W[i] = s * P.p[26][j]; }
  else if (i < OFF_WK2)  { int o = i - OFF_BK1;                  SCALE_T(28, o, s, t); W[i] = s * P.p[27][o] + t; }
  else if (i < OFF_BK2)  { int j = i - OFF_WK2;  int o = j / 48; SCALE_T(34, o, s, t); W[i] = s * P.p[32][j]; }
  else if (i < OFF_WCF)  { int o = i - OFF_BK2;                  SCALE_T(34, o, s, t); W[i] = s * P.p[33][o] + t; }
  else if (i < OFF_BCF)  { int j = i - OFF_WCF;  int o = j / 96; SCALE_T(40, o, s, t); W[i] = s * P.p[38][j]; }
  else if (i < OFF_WE1)  { int o = i - OFF_BCF;                  SCALE_T(40, o, s, t); W[i] = s * P.p[39][o] + t; }
  else if (i < OFF_BE1)  { int j = i - OFF_WE1;  W[i] = P.p[44][j]; }
  else if (i < OFF_WE2)  { int o = i - OFF_BE1;  W[i] = P.p[45][o]; }
  else if (i < OFF_BE2)  { int j = i - OFF_WE2;  W[i] = P.p[46][j]; }
  else if (i < WS_TOTAL) { int o = i - OFF_BE2;  W[i] = P.p[47][o]; }
}

// ---------------- fused per-pixel forward ----------------

__device__ __forceinline__ float gelu_f(float x) {
  return 0.5f * x * (1.f + erff(x * 0.70710678118654752440f));
}

__device__ __forceinline__ void residual_block(float (&X)[48], const float* __restrict__ W) {
  float r[24];
#pragma unroll
  for (int o = 0; o < 24; o++) {
    float a = W[OFF_B1 + o];
#pragma unroll
    for (int c = 0; c < 48; c++) a = fmaf(W[OFF_W1 + o * 48 + c], X[c], a);
    r[o] = fmaxf(a, 0.f);
  }
#pragma unroll
  for (int o = 0; o < 48; o++) {
    float a = W[OFF_B2 + o];
#pragma unroll
    for (int c = 0; c < 24; c++) a = fmaf(W[OFF_W2 + o * 24 + c], r[c], a);
    // xs_new = relu(s*xs_old + (s*(W2 r + b2) + t)), elementwise — no temp array
    X[o] = fmaxf(fmaf(W[OFF_XS + o], X[o], a), 0.f);
  }
}

__device__ __forceinline__ void score_phase(const float (&X)[48], const float (&kk1)[24],
                                            const float (&kk2)[24],
                                            float& s1a, float& s1b, float& s2a, float& s2b,
                                            const float* __restrict__ W) {
  float a10 = 0.f, a11 = 0.f, a20 = 0.f, a21 = 0.f;
#pragma unroll
  for (int o = 0; o < 48; o++) {
    float a = W[OFF_BQ + o];
#pragma unroll
    for (int c = 0; c < 48; c++) a = fmaf(W[OFF_WQ + o * 48 + c], X[c], a);
    if (o < 24) { a10 = fmaf(kk1[o], a, a10);      a20 = fmaf(kk2[o], a, a20); }
    else        { a11 = fmaf(kk1[o - 24], a, a11); a21 = fmaf(kk2[o - 24], a, a21); }
  }
  s1a = a10; s1b = a11; s2a = a20; s2b = a21;
}

__device__ __forceinline__ void value_phase(const float (&X)[48], float w10, float w11,
                                            float w20, float w21, float (&r1)[24],
                                            float (&r2)[24], const float* __restrict__ W) {
#pragma unroll
  for (int o = 0; o < 48; o++) {
    float a = W[OFF_BV + o];
#pragma unroll
    for (int c = 0; c < 48; c++) a = fmaf(W[OFF_WV + o * 48 + c], X[c], a);
    if (o < 24) { r1[o] = fmaf(w10, a, r1[o]);           r2[o] = fmaf(w20, a, r2[o]); }
    else        { r1[o - 24] = fmaf(w11, a, r1[o - 24]); r2[o - 24] = fmaf(w21, a, r2[o - 24]); }
  }
}

__device__ __forceinline__ void softmax4(float (&s)[4]) {
  float m = fmaxf(fmaxf(s[0], s[1]), fmaxf(s[2], s[3]));
  float e0 = __expf(s[0] - m), e1 = __expf(s[1] - m), e2 = __expf(s[2] - m), e3 = __expf(s[3] - m);
  float inv = 1.f / (e0 + e1 + e2 + e3);
  s[0] = e0 * inv; s[1] = e1 * inv; s[2] = e2 * inv; s[3] = e3 * inv;
}

__device__ __forceinline__ void emb48(const float (&t)[48], float (&la)[48],
                                      const float* __restrict__ W) {
  float h[24];
#pragma unroll
  for (int o = 0; o < 24; o++) {
    float a = W[OFF_BE1 + o];
#pragma unroll
    for (int c = 0; c < 48; c++) a = fmaf(W[OFF_WE1 + o * 48 + c], t[c], a);
    h[o] = gelu_f(a);
  }
#pragma unroll
  for (int o = 0; o < 48; o++) {
    float a = W[OFF_BE2 + o];
#pragma unroll
    for (int c = 0; c < 24; c++) a = fmaf(W[OFF_WE2 + o * 24 + c], h[c], a);
    la[o] = a;
  }
}

__device__ __forceinline__ void emb24x2(const float (&r1)[24], const float (&r2)[24],
                                        float (&la)[48], const float* __restrict__ W) {
  float h[24];
#pragma unroll
  for (int o = 0; o < 24; o++) {
    float a = W[OFF_BE1 + o];
#pragma unroll
    for (int c = 0; c < 24; c++) a = fmaf(W[OFF_WE1 + o * 48 + c], r1[c], a);
#pragma unroll
    for (int c = 0; c < 24; c++) a = fmaf(W[OFF_WE1 + o * 48 + 24 + c], r2[c], a);
    h[o] = gelu_f(a);
  }
#pragma unroll
  for (int o = 0; o < 48; o++) {
    float a = W[OFF_BE2 + o];
#pragma unroll
    for (int c = 0; c < 24; c++) a = fmaf(W[OFF_WE2 + o * 24 + c], h[c], a);
    la[o] = a;
  }
}

// attention + emb tail of one iteration: consumes la, produces new la
__device__ __forceinline__ void attn_emb(const float (&X0)[48], const float (&X1)[48],
                                         float (&la)[48], const float* __restrict__ W) {
  // kk1, kk2 from la (la dead afterwards)
  float kk1[24], kk2[24];
#pragma unroll
  for (int o = 0; o < 24; o++) {
    float a1 = W[OFF_BK1 + o], a2 = W[OFF_BK2 + o];
#pragma unroll
    for (int c = 0; c < 48; c++) {
      a1 = fmaf(W[OFF_WK1 + o * 48 + c], la[c], a1);
      a2 = fmaf(W[OFF_WK2 + o * 48 + c], la[c], a2);
    }
    kk1[o] = a1; kk2[o] = a2;
  }

  // scores: s[m] = kk . q_m ; m = {x0 lo, x0 hi, x1 lo, x1 hi}
  float s1[4], s2[4];
  score_phase(X0, kk1, kk2, s1[0], s1[1], s2[0], s2[1], W);
  score_phase(X1, kk1, kk2, s1[2], s1[3], s2[2], s2[3], W);
  softmax4(s1);
  softmax4(s2);

  // refs: r_j[c] = sum_m att_j[m] * v_m[c]
  float r1[24], r2[24];
#pragma unroll
  for (int c = 0; c < 24; c++) { r1[c] = 0.f; r2[c] = 0.f; }
  value_phase(X0, s1[0], s1[1], s2[0], s2[1], r1, r2, W);
  value_phase(X1, s1[2], s1[3], s2[2], s2[3], r1, r2, W);

  // la = emb(concat(r1, r2))
  emb24x2(r1, r2, la, W);
}

__global__ __attribute__((amdgpu_waves_per_eu(2, 2))) __launch_bounds__(256)
void fused_main(const float* __restrict__ x0g,
                const float* __restrict__ x1g,
                const float* __restrict__ W,
                float* __restrict__ out) {
  int p = blockIdx.x * 256 + threadIdx.x;
  int b = p >> 14;           // hw = 16384
  int n = p & (HWS - 1);
  const float* px0 = x0g + (size_t)b * 48 * HWS + n;
  const float* px1 = x1g + (size_t)b * 48 * HWS + n;

  float X0[48], X1[48], la[48];
#pragma unroll
  for (int c = 0; c < 48; c++) { X0[c] = px0[c * HWS]; X1[c] = px1[c * HWS]; }

  // ---- iteration 0, peeled (contains the cf+emb la initialization) ----
  residual_block(X0, W);
  residual_block(X1, W);
  {
    float t[48];
#pragma unroll
    for (int o = 0; o < 48; o++) {
      float a = W[OFF_BCF + o];
#pragma unroll
      for (int c = 0; c < 48; c++) a = fmaf(W[OFF_WCF + o * 96 + c], X0[c], a);
#pragma unroll
      for (int c = 0; c < 48; c++) a = fmaf(W[OFF_WCF + o * 96 + 48 + c], X1[c], a);
      t[o] = fmaxf(a, 0.f);
    }
    emb48(t, la, W);
  }
  attn_emb(X0, X1, la, W);

  // ---- iterations 1..3 ----
#pragma unroll 1
  for (int k = 1; k < 4; k++) {
    residual_block(X0, W);
    residual_block(X1, W);
    attn_emb(X0, X1, la, W);
  }

  float* po = out + (size_t)b * 48 * HWS + n;
#pragma unroll
  for (int c = 0; c < 48; c++) po[c * HWS] = la[c];
}

extern "C" void kernel_launch(void* const* d_in, const int* in_sizes, int n_in,
                              void* d_out, int out_size, void* d_ws, size_t ws_size,
                              hipStream_t stream) {
  PtrPack P;
  for (int i = 0; i < 48; i++) P.p[i] = (const float*)d_in[i];
  float* W = (float*)d_ws;

  fold_kernel<<<(WS_TOTAL + 255) / 256, 256, 0, stream>>>(P, W);
  fused_main<<<NPIX / 256, 256, 0, stream>>>(P.p[0], P.p[1], W, (float*)d_out);
}

// Round 4
// 1140.777 us; speedup vs baseline: 2.2880x; 2.2880x over previous
//
#include <hip/hip_runtime.h>
#include <stdint.h>
#include <math.h>

#define HWS 16384
#define NPIX (16 * HWS)
#define T 128

// float offsets into d_ws. All weight matrices stored TRANSPOSED: [cin][out],
// so c-outer/o-inner accumulation reads contiguous runs of `out` floats.
enum {
  OFF_W1  = 0,      // [48][24] rb conv1 (bn-folded)
  OFF_B1  = 1152,   // 24
  OFF_W2  = 1176,   // [24][48] rb conv2 (post-residual bn folded)
  OFF_B2  = 2328,   // 48
  OFF_XS  = 2376,   // 48  bn scale applied to xs in residual add
  OFF_WQ  = 2424,   // [48][48]
  OFF_BQ  = 4728,   // 48
  OFF_WV  = 4776,   // [48][48]
  OFF_BV  = 7080,   // 48
  OFF_WK1 = 7128,   // [48][24]
  OFF_BK1 = 8280,   // 24
  OFF_WK2 = 8304,   // [48][24]
  OFF_BK2 = 9456,   // 24
  OFF_WCF = 9480,   // [96][48]
  OFF_BCF = 14088,  // 48
  OFF_WE1 = 14136,  // [48][24] emb conv1 (no bn)
  OFF_BE1 = 15288,  // 24
  OFF_WE2 = 15312,  // [24][48]
  OFF_BE2 = 16464,  // 48
  WS_TOTAL = 16512
};

struct PtrPack { const float* p[48]; };

// bn fold: s = g/sqrt(v+eps), t = beta - m*s;  bn(conv(x,W,b)) = (s.W)x + (s.b + t)
#define SCALE_T(bnb, o, s, t)                                       \
  {                                                                 \
    float g_ = P.p[(bnb)][(o)], be_ = P.p[(bnb) + 1][(o)];          \
    float m_ = P.p[(bnb) + 2][(o)], v_ = P.p[(bnb) + 3][(o)];       \
    s = g_ / sqrtf(v_ + 1e-5f);                                     \
    t = be_ - m_ * s;                                               \
  }

__global__ void fold_kernel(PtrPack P, float* __restrict__ W) {
  int i = blockIdx.x * blockDim.x + threadIdx.x;
  float s, t;
  if (i < OFF_B1)        { int j = i;            int ci = j / 24, o = j % 24; SCALE_T(4,  o, s, t); W[i] = s * P.p[2][o * 48 + ci]; }
  else if (i < OFF_W2)   { int o = i - OFF_B1;                                SCALE_T(4,  o, s, t); W[i] = s * P.p[3][o] + t; }
  else if (i < OFF_B2)   { int j = i - OFF_W2;   int ci = j / 48, o = j % 48; SCALE_T(10, o, s, t); W[i] = s * P.p[8][o * 24 + ci]; }
  else if (i < OFF_XS)   { int o = i - OFF_B2;                                SCALE_T(10, o, s, t); W[i] = s * P.p[9][o] + t; }
  else if (i < OFF_WQ)   { int o = i - OFF_XS;                                SCALE_T(10, o, s, t); W[i] = s; }
  else if (i < OFF_BQ)   { int j = i - OFF_WQ;   int ci = j / 48, o = j % 48; SCALE_T(16, o, s, t); W[i] = s * P.p[14][o * 48 + ci]; }
  else if (i < OFF_WV)   { int o = i - OFF_BQ;                                SCALE_T(16, o, s, t); W[i] = s * P.p[15][o] + t; }
  else if (i < OFF_BV)   { int j = i - OFF_WV;   int ci = j / 48, o = j % 48; SCALE_T(22, o, s, t); W[i] = s * P.p[20][o * 48 + ci]; }
  else if (i < OFF_WK1)  { int o = i - OFF_BV;                                SCALE_T(22, o, s, t); W[i] = s * P.p[21][o] + t; }
  else if (i < OFF_BK1)  { int j = i - OFF_WK1;  int ci = j / 24, o = j % 24; SCALE_T(28, o, s, t); W[i] = s * P.p[26][o * 48 + ci]; }
  else if (i < OFF_WK2)  { int o = i - OFF_BK1;                               SCALE_T(28, o, s, t); W[i] = s * P.p[27][o] + t; }
  else if (i < OFF_BK2)  { int j = i - OFF_WK2;  int ci = j / 24, o = j % 24; SCALE_T(34, o, s, t); W[i] = s * P.p[32][o * 48 + ci]; }
  else if (i < OFF_WCF)  { int o = i - OFF_BK2;                               SCALE_T(34, o, s, t); W[i] = s * P.p[33][o] + t; }
  else if (i < OFF_BCF)  { int j = i - OFF_WCF;  int ci = j / 48, o = j % 48; SCALE_T(40, o, s, t); W[i] = s * P.p[38][o * 96 + ci]; }
  else if (i < OFF_WE1)  { int o = i - OFF_BCF;                               SCALE_T(40, o, s, t); W[i] = s * P.p[39][o] + t; }
  else if (i < OFF_BE1)  { int j = i - OFF_WE1;  int ci = j / 24, o = j % 24; W[i] = P.p[44][o * 48 + ci]; }
  else if (i < OFF_WE2)  { int o = i - OFF_BE1;  W[i] = P.p[45][o]; }
  else if (i < OFF_BE2)  { int j = i - OFF_WE2;  int ci = j / 48, o = j % 48; W[i] = P.p[46][o * 24 + ci]; }
  else if (i < WS_TOTAL) { int o = i - OFF_BE2;  W[i] = P.p[47][o]; }
}

// ---------------- fused per-pixel forward, X-state in LDS ----------------

__device__ __forceinline__ float gelu_f(float x) {
  return 0.5f * x * (1.f + erff(x * 0.70710678118654752440f));
}

__global__ __launch_bounds__(T) void fused_main(const float* __restrict__ x0g,
                                                const float* __restrict__ x1g,
                                                const float* __restrict__ W,
                                                float* __restrict__ out) {
  // Per-thread private column; [c][tid] layout -> lane-consecutive addresses,
  // conflict-free, and no cross-thread sharing (no barriers needed).
  __shared__ float Xl[2][48][T];
  const int tid = threadIdx.x;
  const int p = blockIdx.x * T + tid;
  const int b = p >> 14;  // hw = 16384
  const int n = p & (HWS - 1);

  {
    const float* px0 = x0g + (size_t)b * 48 * HWS + n;
    const float* px1 = x1g + (size_t)b * 48 * HWS + n;
#pragma unroll 4
    for (int c = 0; c < 48; c++) {
      Xl[0][c][tid] = px0[(size_t)c * HWS];
      Xl[1][c][tid] = px1[(size_t)c * HWS];
    }
  }

  float la[48];

#pragma unroll 1
  for (int k = 0; k < 4; k++) {
    // ---- residual blocks (in-place on Xl), c-outer accumulation ----
#pragma unroll 1
    for (int s = 0; s < 2; s++) {
      float r[24];
#pragma unroll
      for (int o = 0; o < 24; o++) r[o] = W[OFF_B1 + o];
#pragma unroll 2
      for (int c = 0; c < 48; c++) {
        float xc = Xl[s][c][tid];
#pragma unroll
        for (int o = 0; o < 24; o++) r[o] = fmaf(W[OFF_W1 + c * 24 + o], xc, r[o]);
      }
#pragma unroll
      for (int o = 0; o < 24; o++) r[o] = fmaxf(r[o], 0.f);

      float acc[48];
#pragma unroll
      for (int o = 0; o < 48; o++) acc[o] = W[OFF_B2 + o];
#pragma unroll 2
      for (int c = 0; c < 24; c++) {
#pragma unroll
        for (int o = 0; o < 48; o++) acc[o] = fmaf(W[OFF_W2 + c * 48 + o], r[c], acc[o]);
      }
#pragma unroll
      for (int o = 0; o < 48; o++) {
        float xo = Xl[s][o][tid];
        Xl[s][o][tid] = fmaxf(fmaf(W[OFF_XS + o], xo, acc[o]), 0.f);
      }
    }

    // ---- k==0: la = emb(relu(cf @ concat(X0,X1))) ----
    if (k == 0) {
      float tv[48];
#pragma unroll
      for (int o = 0; o < 48; o++) tv[o] = W[OFF_BCF + o];
#pragma unroll 1
      for (int s = 0; s < 2; s++) {
#pragma unroll 2
        for (int c = 0; c < 48; c++) {
          float xc = Xl[s][c][tid];
#pragma unroll
          for (int o = 0; o < 48; o++) tv[o] = fmaf(W[OFF_WCF + (s * 48 + c) * 48 + o], xc, tv[o]);
        }
      }
#pragma unroll
      for (int o = 0; o < 48; o++) tv[o] = fmaxf(tv[o], 0.f);

      float h[24];
#pragma unroll
      for (int o = 0; o < 24; o++) h[o] = W[OFF_BE1 + o];
#pragma unroll 2
      for (int c = 0; c < 48; c++) {
#pragma unroll
        for (int o = 0; o < 24; o++) h[o] = fmaf(W[OFF_WE1 + c * 24 + o], tv[c], h[o]);
      }
#pragma unroll
      for (int o = 0; o < 24; o++) h[o] = gelu_f(h[o]);
#pragma unroll
      for (int o = 0; o < 48; o++) la[o] = W[OFF_BE2 + o];
#pragma unroll 2
      for (int c = 0; c < 24; c++) {
#pragma unroll
        for (int o = 0; o < 48; o++) la[o] = fmaf(W[OFF_WE2 + c * 48 + o], h[c], la[o]);
      }
    }

    // ---- kk1, kk2 from la (la dead afterwards) ----
    float kk1[24], kk2[24];
#pragma unroll
    for (int o = 0; o < 24; o++) { kk1[o] = W[OFF_BK1 + o]; kk2[o] = W[OFF_BK2 + o]; }
#pragma unroll 2
    for (int c = 0; c < 48; c++) {
      float lc = la[c];
#pragma unroll
      for (int o = 0; o < 24; o++) {
        kk1[o] = fmaf(W[OFF_WK1 + c * 24 + o], lc, kk1[o]);
        kk2[o] = fmaf(W[OFF_WK2 + c * 24 + o], lc, kk2[o]);
      }
    }

    // ---- scores: m order = {x0 lo, x0 hi, x1 lo, x1 hi} ----
    float s1[4], s2[4];
#pragma unroll
    for (int s = 0; s < 2; s++) {
      float q[48];
#pragma unroll
      for (int o = 0; o < 48; o++) q[o] = W[OFF_BQ + o];
#pragma unroll 2
      for (int c = 0; c < 48; c++) {
        float xc = Xl[s][c][tid];
#pragma unroll
        for (int o = 0; o < 48; o++) q[o] = fmaf(W[OFF_WQ + c * 48 + o], xc, q[o]);
      }
      float a10 = 0.f, a11 = 0.f, a20 = 0.f, a21 = 0.f;
#pragma unroll
      for (int o = 0; o < 24; o++) {
        a10 = fmaf(kk1[o], q[o], a10);
        a20 = fmaf(kk2[o], q[o], a20);
        a11 = fmaf(kk1[o], q[24 + o], a11);
        a21 = fmaf(kk2[o], q[24 + o], a21);
      }
      s1[2 * s] = a10; s1[2 * s + 1] = a11;
      s2[2 * s] = a20; s2[2 * s + 1] = a21;
    }
    // softmax over the 4 scores (per pixel)
    {
      float m1 = fmaxf(fmaxf(s1[0], s1[1]), fmaxf(s1[2], s1[3]));
      float e0 = __expf(s1[0] - m1), e1 = __expf(s1[1] - m1), e2 = __expf(s1[2] - m1), e3 = __expf(s1[3] - m1);
      float inv = 1.f / (e0 + e1 + e2 + e3);
      s1[0] = e0 * inv; s1[1] = e1 * inv; s1[2] = e2 * inv; s1[3] = e3 * inv;
      float m2 = fmaxf(fmaxf(s2[0], s2[1]), fmaxf(s2[2], s2[3]));
      float f0 = __expf(s2[0] - m2), f1 = __expf(s2[1] - m2), f2 = __expf(s2[2] - m2), f3 = __expf(s2[3] - m2);
      float jnv = 1.f / (f0 + f1 + f2 + f3);
      s2[0] = f0 * jnv; s2[1] = f1 * jnv; s2[2] = f2 * jnv; s2[3] = f3 * jnv;
    }

    // ---- values: r_j[c] = sum_m att_j[m] * v_m[c] ----
    float r1[24], r2[24];
#pragma unroll
    for (int o = 0; o < 24; o++) { r1[o] = 0.f; r2[o] = 0.f; }
#pragma unroll
    for (int s = 0; s < 2; s++) {
      float v[48];
#pragma unroll
      for (int o = 0; o < 48; o++) v[o] = W[OFF_BV + o];
#pragma unroll 2
      for (int c = 0; c < 48; c++) {
        float xc = Xl[s][c][tid];
#pragma unroll
        for (int o = 0; o < 48; o++) v[o] = fmaf(W[OFF_WV + c * 48 + o], xc, v[o]);
      }
#pragma unroll
      for (int o = 0; o < 24; o++) {
        r1[o] = fmaf(s1[2 * s], v[o], r1[o]);
        r1[o] = fmaf(s1[2 * s + 1], v[24 + o], r1[o]);
        r2[o] = fmaf(s2[2 * s], v[o], r2[o]);
        r2[o] = fmaf(s2[2 * s + 1], v[24 + o], r2[o]);
      }
    }

    // ---- la = emb(concat(r1, r2)) ----
    {
      float h[24];
#pragma unroll
      for (int o = 0; o < 24; o++) h[o] = W[OFF_BE1 + o];
#pragma unroll 2
      for (int c = 0; c < 24; c++) {
#pragma unroll
        for (int o = 0; o < 24; o++) {
          h[o] = fmaf(W[OFF_WE1 + c * 24 + o], r1[c], h[o]);
          h[o] = fmaf(W[OFF_WE1 + (24 + c) * 24 + o], r2[c], h[o]);
        }
      }
#pragma unroll
      for (int o = 0; o < 24; o++) h[o] = gelu_f(h[o]);
#pragma unroll
      for (int o = 0; o < 48; o++) la[o] = W[OFF_BE2 + o];
#pragma unroll 2
      for (int c = 0; c < 24; c++) {
#pragma unroll
        for (int o = 0; o < 48; o++) la[o] = fmaf(W[OFF_WE2 + c * 48 + o], h[c], la[o]);
      }
    }
  }

  float* po = out + (size_t)b * 48 * HWS + n;
#pragma unroll 4
  for (int c = 0; c < 48; c++) po[(size_t)c * HWS] = la[c];
}

extern "C" void kernel_launch(void* const* d_in, const int* in_sizes, int n_in,
                              void* d_out, int out_size, void* d_ws, size_t ws_size,
                              hipStream_t stream) {
  PtrPack P;
  for (int i = 0; i < 48; i++) P.p[i] = (const float*)d_in[i];
  float* W = (float*)d_ws;

  fold_kernel<<<(WS_TOTAL + 255) / 256, 256, 0, stream>>>(P, W);
  fused_main<<<NPIX / T, T, 0, stream>>>(P.p[0], P.p[1], W, (float*)d_out);
}